// Round 1
// baseline (428.579 us; speedup 1.0000x reference)
//
#include <hip/hip_runtime.h>
#include <cstdint>
#include <cstddef>

#define S_LEN 4096
#define B_SZ 16
#define H2D 1024
#define CHUNKS 64                      // s-chunks per batch
#define WPB 4                          // waves per block (256 threads)
#define P_PER_B (CHUNKS * WPB)         // 256 partials per batch
#define S_PER_WAVE (S_LEN / P_PER_B)   // 16 s per wave

__device__ __forceinline__ void load16(const float* __restrict__ p, float v[16]) {
    const float4* q = (const float4*)p;
    float4 x0 = q[0], x1 = q[1], x2 = q[2], x3 = q[3];
    v[0] = x0.x; v[1] = x0.y; v[2]  = x0.z; v[3]  = x0.w;
    v[4] = x1.x; v[5] = x1.y; v[6]  = x1.z; v[7]  = x1.w;
    v[8] = x2.x; v[9] = x2.y; v[10] = x2.z; v[11] = x2.w;
    v[12] = x3.x; v[13] = x3.y; v[14] = x3.z; v[15] = x3.w;
}

// altered_state[b][i] = attn_b[i] + sum_j state[b][j] * attn_w[i][j]
// one wave per output column i; attn_w row cached in registers, loop over b.
__global__ __launch_bounds__(256) void k_altered(const float* __restrict__ state,
                                                 const float* __restrict__ attn_w,
                                                 const float* __restrict__ attn_b,
                                                 float* __restrict__ altered) {
    const int i = (blockIdx.x * blockDim.x + threadIdx.x) >> 6;  // 0..1023
    const int lane = threadIdx.x & 63;
    float r[16];
    load16(attn_w + (size_t)i * H2D + lane * 16, r);
    const float bias = attn_b[i];
    for (int b = 0; b < B_SZ; ++b) {
        float s[16];
        load16(state + b * H2D + lane * 16, s);
        float p = 0.f;
#pragma unroll
        for (int k = 0; k < 16; ++k) p += r[k] * s[k];
#pragma unroll
        for (int off = 32; off; off >>= 1) p += __shfl_xor(p, off, 64);
        if (lane == 0) altered[b * H2D + i] = p + bias;
    }
}

// Flash-style single pass over encoder_outputs: per-wave online softmax.
// Wave layout: 64 lanes x 16 floats = H2. Each wave owns S_PER_WAVE timesteps.
__global__ __launch_bounds__(256) void k_flash(const float* __restrict__ enc,
                                               const float* __restrict__ altered,
                                               float* __restrict__ w_raw,
                                               float* __restrict__ pm,
                                               float* __restrict__ pl,
                                               float* __restrict__ pacc) {
    const int b = blockIdx.y;
    const int wave = threadIdx.x >> 6;
    const int lane = threadIdx.x & 63;
    const int p_idx = blockIdx.x * WPB + wave;  // 0..P_PER_B-1

    float a[16];
    load16(altered + b * H2D + lane * 16, a);

    float m = -1e30f, l = 0.f;
    float acc[16];
#pragma unroll
    for (int i = 0; i < 16; ++i) acc[i] = 0.f;

    const int s_start = blockIdx.x * (S_LEN / CHUNKS) + wave;

    for (int k = 0; k < S_PER_WAVE; k += 2) {
        const int sA = s_start + WPB * k;
        const int sB = sA + WPB;
        float eA[16], eB[16];
        load16(enc + ((size_t)sA * B_SZ + b) * H2D + lane * 16, eA);
        load16(enc + ((size_t)sB * B_SZ + b) * H2D + lane * 16, eB);
        float pA = 0.f, pB = 0.f;
#pragma unroll
        for (int i = 0; i < 16; ++i) { pA += a[i] * eA[i]; pB += a[i] * eB[i]; }
#pragma unroll
        for (int off = 32; off; off >>= 1) {
            pA += __shfl_xor(pA, off, 64);
            pB += __shfl_xor(pB, off, 64);
        }
        if (lane == 0) {
            w_raw[b * S_LEN + sA] = pA;
            w_raw[b * S_LEN + sB] = pB;
        }
        // online-softmax merge of sA
        float mn = fmaxf(m, pA);
        float sc = __expf(m - mn);
        float ex = __expf(pA - mn);
        l = l * sc + ex;
#pragma unroll
        for (int i = 0; i < 16; ++i) acc[i] = acc[i] * sc + ex * eA[i];
        m = mn;
        // merge sB
        mn = fmaxf(m, pB);
        sc = __expf(m - mn);
        ex = __expf(pB - mn);
        l = l * sc + ex;
#pragma unroll
        for (int i = 0; i < 16; ++i) acc[i] = acc[i] * sc + ex * eB[i];
        m = mn;
    }

    const size_t pi = (size_t)(b * P_PER_B + p_idx);
    if (lane == 0) { pm[pi] = m; pl[pi] = l; }
    float4* pa = (float4*)(pacc + pi * H2D + lane * 16);
    pa[0] = make_float4(acc[0],  acc[1],  acc[2],  acc[3]);
    pa[1] = make_float4(acc[4],  acc[5],  acc[6],  acc[7]);
    pa[2] = make_float4(acc[8],  acc[9],  acc[10], acc[11]);
    pa[3] = make_float4(acc[12], acc[13], acc[14], acc[15]);
}

// Per-batch reduce of partial (m, l): global max M_b, Z_b, per-partial coef.
__global__ __launch_bounds__(P_PER_B) void k_reduce(const float* __restrict__ pm,
                                                    const float* __restrict__ pl,
                                                    float* __restrict__ cexp,
                                                    float* __restrict__ MZ) {
    const int b = blockIdx.x, t = threadIdx.x;
    __shared__ float sm[P_PER_B];
    const float mv = pm[b * P_PER_B + t];
    sm[t] = mv;
    __syncthreads();
    for (int o = P_PER_B / 2; o; o >>= 1) {
        if (t < o) sm[t] = fmaxf(sm[t], sm[t + o]);
        __syncthreads();
    }
    const float M = sm[0];
    __syncthreads();
    const float e = __expf(mv - M);
    sm[t] = e * pl[b * P_PER_B + t];
    __syncthreads();
    for (int o = P_PER_B / 2; o; o >>= 1) {
        if (t < o) sm[t] += sm[t + o];
        __syncthreads();
    }
    cexp[b * P_PER_B + t] = e;
    if (t == 0) {
        MZ[b * 2]     = M;
        MZ[b * 2 + 1] = 1.f / sm[0];
    }
}

// attention_applied[b][d] = invZ_b * sum_p cexp[b][p] * pacc[b][p][d]
__global__ __launch_bounds__(64) void k_combine(const float* __restrict__ pacc,
                                                const float* __restrict__ cexp,
                                                const float* __restrict__ MZ,
                                                float* __restrict__ out_attn) {
    const int b = blockIdx.x >> 4;                   // 16 blocks per batch
    const int d = ((blockIdx.x & 15) << 6) + threadIdx.x;
    float sum = 0.f;
    const float* base = pacc + (size_t)b * P_PER_B * H2D + d;
    const float* c = cexp + b * P_PER_B;
#pragma unroll 8
    for (int p = 0; p < P_PER_B; ++p) {
        sum += c[p] * base[(size_t)p * H2D];
    }
    out_attn[b * H2D + d] = sum * MZ[b * 2 + 1];
}

// normalized_weights[b][s] = exp(w_raw[b][s] - M_b) * invZ_b
__global__ __launch_bounds__(256) void k_norm(const float* __restrict__ w_raw,
                                              const float* __restrict__ MZ,
                                              float* __restrict__ out_nw) {
    const int idx = blockIdx.x * 256 + threadIdx.x;  // 0..65535
    const int b = idx >> 12;                         // / S_LEN
    out_nw[idx] = __expf(w_raw[idx] - MZ[b * 2]) * MZ[b * 2 + 1];
}

extern "C" void kernel_launch(void* const* d_in, const int* in_sizes, int n_in,
                              void* d_out, int out_size, void* d_ws, size_t ws_size,
                              hipStream_t stream) {
    const float* enc    = (const float*)d_in[0];  // [S, B, 2H]
    const float* state  = (const float*)d_in[1];  // [B, 2H]
    // d_in[2] previous_attention, d_in[5] time_w, d_in[6] time_b: dead branch, unused
    const float* attn_w = (const float*)d_in[3];  // [2H, 2H]
    const float* attn_b = (const float*)d_in[4];  // [2H]

    float* ws = (float*)d_ws;
    float* altered = ws;              // 16384 floats
    float* w_raw   = ws + 16384;      // 65536
    float* pm      = ws + 81920;      // 4096
    float* pl      = ws + 86016;      // 4096
    float* cexp    = ws + 90112;      // 4096
    float* MZ      = ws + 94208;      // 32 (padded to 1024)
    float* pacc    = ws + 95232;      // 16*256*1024 = 4194304 floats (16 MB)
    // total ws use: ~16.4 MB

    float* out_attn = (float*)d_out;               // [B, 2H]
    float* out_nw   = (float*)d_out + B_SZ * H2D;  // [B, S]

    hipLaunchKernelGGL(k_altered, dim3(256), dim3(256), 0, stream,
                       state, attn_w, attn_b, altered);
    hipLaunchKernelGGL(k_flash, dim3(CHUNKS, B_SZ), dim3(256), 0, stream,
                       enc, altered, w_raw, pm, pl, pacc);
    hipLaunchKernelGGL(k_reduce, dim3(B_SZ), dim3(P_PER_B), 0, stream,
                       pm, pl, cexp, MZ);
    hipLaunchKernelGGL(k_combine, dim3(B_SZ * H2D / 64), dim3(64), 0, stream,
                       pacc, cexp, MZ, out_attn);
    hipLaunchKernelGGL(k_norm, dim3(B_SZ * S_LEN / 256), dim3(256), 0, stream,
                       w_raw, MZ, out_nw);
}